// Round 2
// baseline (1618.833 us; speedup 1.0000x reference)
//
#include <hip/hip_runtime.h>

typedef unsigned int u32;

// ---- workspace layout (float offsets) ----
#define WS_WSG   0        // 64x256: Wsrc @ Wgate   [k][j]
#define WS_WDG   16384    // 64x256: Wdst @ Wgate   [k][j]
#define WS_WEG   32768    // 8x256 : Wenc @ Wgate   [m][j]
#define WS_BALL  34816    // 256   : (benc+bsrc+bdst) @ Wgate + bgate
#define WS_ETOT  35072    // 1 int : total valid edges (written by scan_k)
#define WS_GS    35328    // N x 256 (GS), then N x 256 (GD), then CSR area

// ---------------------------------------------------------------- zero out
__global__ void zero_k(float* p, int n) {
    int i = blockIdx.x * blockDim.x + threadIdx.x;
    int st = gridDim.x * blockDim.x;
    for (; i < n; i += st) p[i] = 0.0f;
}

// ---------------------------------------------------------------- compose weights
// 73 blocks x 256 threads. Rows 0..63: WsG & WdG; 64..71: WeG; 72: bias row.
__global__ void compose_k(const float* __restrict__ Wsrc, const float* __restrict__ Wdst,
                          const float* __restrict__ Wenc, const float* __restrict__ benc,
                          const float* __restrict__ bsrc, const float* __restrict__ bdst,
                          const float* __restrict__ Wgate, const float* __restrict__ bgate,
                          float* __restrict__ ws) {
    const int j = threadIdx.x;           // 0..255
    const int r = blockIdx.x;            // 0..72
    if (r < 64) {
        float a = 0.f, b = 0.f;
        for (int c = 0; c < 64; ++c) {
            const float wg = Wgate[c * 256 + j];
            a += Wsrc[r * 64 + c] * wg;
            b += Wdst[r * 64 + c] * wg;
        }
        ws[WS_WSG + r * 256 + j] = a;
        ws[WS_WDG + r * 256 + j] = b;
    } else if (r < 72) {
        const int m = r - 64;
        float a = 0.f;
        for (int c = 0; c < 64; ++c) a += Wenc[m * 64 + c] * Wgate[c * 256 + j];
        ws[WS_WEG + m * 256 + j] = a;
    } else {
        float a = bgate[j];
        for (int c = 0; c < 64; ++c)
            a += (benc[c] + bsrc[c] + bdst[c]) * Wgate[c * 256 + j];
        ws[WS_BALL + j] = a;
    }
}

// ---------------------------------------------------------------- node precompute v2
// G[n][j] = sum_k emb[n][k] * Wg[k][j]. 256 threads, 4 nodes/iter,
// float4 broadcast reads of emb; 64KB LDS -> 2 blocks/CU.
__global__ __launch_bounds__(256, 2) void nodepre2_k(
    const float* __restrict__ emb, const float* __restrict__ Wg,
    float* __restrict__ G, int N) {
    __shared__ float sW[16384];                  // [k][j], 64 KB
    __shared__ __align__(16) float sEm[256];     // 4 node rows
    for (int i = threadIdx.x * 4; i < 16384; i += 1024)
        *(float4*)&sW[i] = *(const float4*)&Wg[i];
    const int j = threadIdx.x;
    const int ngr = (N + 3) >> 2;
    for (int g = blockIdx.x; g < ngr; g += gridDim.x) {
        const int n0 = g * 4;
        const int nn = n0 + (j >> 6);
        sEm[j] = (nn < N) ? emb[nn * 64 + (j & 63)] : 0.f;
        __syncthreads();
        float a0 = 0.f, a1 = 0.f, a2 = 0.f, a3 = 0.f;
        #pragma unroll
        for (int k4 = 0; k4 < 16; ++k4) {
            const float4 e0 = *(const float4*)&sEm[4 * k4];
            const float4 e1 = *(const float4*)&sEm[64 + 4 * k4];
            const float4 e2 = *(const float4*)&sEm[128 + 4 * k4];
            const float4 e3 = *(const float4*)&sEm[192 + 4 * k4];
            const float w0 = sW[(4 * k4 + 0) * 256 + j];
            const float w1 = sW[(4 * k4 + 1) * 256 + j];
            const float w2 = sW[(4 * k4 + 2) * 256 + j];
            const float w3 = sW[(4 * k4 + 3) * 256 + j];
            a0 += e0.x * w0 + e0.y * w1 + e0.z * w2 + e0.w * w3;
            a1 += e1.x * w0 + e1.y * w1 + e1.z * w2 + e1.w * w3;
            a2 += e2.x * w0 + e2.y * w1 + e2.z * w2 + e2.w * w3;
            a3 += e3.x * w0 + e3.y * w1 + e3.z * w2 + e3.w * w3;
        }
        __syncthreads();
        if (n0 < N)     G[(size_t)n0 * 256 + j] = a0;
        if (n0 + 1 < N) G[(size_t)(n0 + 1) * 256 + j] = a1;
        if (n0 + 2 < N) G[(size_t)(n0 + 2) * 256 + j] = a2;
        if (n0 + 3 < N) G[(size_t)(n0 + 3) * 256 + j] = a3;
    }
}

// ---------------------------------------------------------------- CSR: count
__global__ void count_k(const int* __restrict__ src, const int* __restrict__ dst,
                        int* __restrict__ cnt, int N, int E) {
    __shared__ int sFl[2];
    if (threadIdx.x == 0) {
        const u32* ps = (const u32*)src;
        const u32* pd = (const u32*)dst;
        int s64 = 1, d64 = 1;
        for (int i = 1; i < 128; i += 2) {
            if (ps[i] != 0u) s64 = 0;
            if (pd[i] != 0u) d64 = 0;
        }
        sFl[0] = s64;
        sFl[1] = d64;
    }
    __syncthreads();
    const int i64s = sFl[0], i64d = sFl[1];
    for (int e = blockIdx.x * blockDim.x + threadIdx.x; e < E;
         e += gridDim.x * blockDim.x) {
        const int s = i64s ? src[2 * e] : src[e];
        const int t = i64d ? dst[2 * e] : dst[e];
        if (s < 0 || s >= N || t < 0 || t >= N) continue;
        atomicAdd(&cnt[s], 1);
    }
}

// ---------------------------------------------------------------- CSR: scan
// Single block: cnt[] -> exclusive prefix (cursor), total -> etot.
__global__ __launch_bounds__(1024) void scan_k(int* __restrict__ cnt,
                                               int* __restrict__ etot, int N) {
    __shared__ int sp[1024];
    const int tid = threadIdx.x;
    const int chunk = (N + 1023) >> 10;
    const int beg = tid * chunk;
    int end = beg + chunk; if (end > N) end = N;
    int sum = 0;
    for (int i = beg; i < end; ++i) sum += cnt[i];
    sp[tid] = sum;
    __syncthreads();
    for (int off = 1; off < 1024; off <<= 1) {
        const int v = (tid >= off) ? sp[tid - off] : 0;
        __syncthreads();
        sp[tid] += v;
        __syncthreads();
    }
    int cur = (tid == 0) ? 0 : sp[tid - 1];
    for (int i = beg; i < end; ++i) {
        const int c = cnt[i];
        cnt[i] = cur;
        cur += c;
    }
    if (tid == 1023) *etot = sp[1023];
}

// ---------------------------------------------------------------- CSR: fill
// Writes src-sorted edge table: ss[pos]=s, tbl[pos]={r0,r1,r2,dst-bits}.
__global__ void fill_k(const int* __restrict__ src, const int* __restrict__ dst,
                       const float* __restrict__ r_ij, int* __restrict__ cursor,
                       int* __restrict__ ss, float4* __restrict__ tbl,
                       int N, int E) {
    __shared__ int sFl[2];
    if (threadIdx.x == 0) {
        const u32* ps = (const u32*)src;
        const u32* pd = (const u32*)dst;
        int s64 = 1, d64 = 1;
        for (int i = 1; i < 128; i += 2) {
            if (ps[i] != 0u) s64 = 0;
            if (pd[i] != 0u) d64 = 0;
        }
        sFl[0] = s64;
        sFl[1] = d64;
    }
    __syncthreads();
    const int i64s = sFl[0], i64d = sFl[1];
    for (int e = blockIdx.x * blockDim.x + threadIdx.x; e < E;
         e += gridDim.x * blockDim.x) {
        const int s = i64s ? src[2 * e] : src[e];
        const int t = i64d ? dst[2 * e] : dst[e];
        if (s < 0 || s >= N || t < 0 || t >= N) continue;
        const float r0 = r_ij[e * 3 + 0];
        const float r1 = r_ij[e * 3 + 1];
        const float r2 = r_ij[e * 3 + 2];
        const int pos = atomicAdd(&cursor[s], 1);
        ss[pos] = s;
        tbl[pos] = make_float4(r0, r1, r2, __int_as_float(t));
    }
}

// ---------------------------------------------------------------- edge kernel (sorted)
// One wave per contiguous chunk of src-sorted edges. Accumulates the raw
// message in registers; atomics only on src-change (~E/deg + #waves flushes).
__global__ __launch_bounds__(256, 8) void edge_sorted_k(
    const float* __restrict__ GS, const float* __restrict__ GD,
    const float* __restrict__ z0g, const float* __restrict__ z1g,
    const int* __restrict__ ss, const float4* __restrict__ tbl,
    const float* __restrict__ WeG, const float* __restrict__ ball,
    const int* __restrict__ etot, float* __restrict__ out, int N) {
    __shared__ float sWe[2048];   // 8 KB
    __shared__ float sBall[256];  // 1 KB
    __shared__ int sE[1];
    for (int i = threadIdx.x; i < 2048; i += 256) sWe[i] = WeG[i];
    sBall[threadIdx.x] = ball[threadIdx.x];
    if (threadIdx.x == 0) sE[0] = *etot;
    __syncthreads();

    const int Et = sE[0];
    const int wid = threadIdx.x >> 6, lane = threadIdx.x & 63;
    const int nw = gridDim.x * 4;
    const int w = blockIdx.x * 4 + wid;
    const int chunk = (Et + nw - 1) / nw;
    const int beg = w * chunk;
    int end = beg + chunk; if (end > Et) end = Et;
    if (beg >= end) return;

    const float bl0 = sBall[lane], bl1 = sBall[64 + lane];
    const float bl2 = sBall[128 + lane], bl3 = sBall[192 + lane];

    int cur = -1;
    float accS = 0.f, accV0 = 0.f, accV1 = 0.f, accV2 = 0.f;
    float gs0 = 0.f, gs1 = 0.f, gs2 = 0.f, gs3 = 0.f;

    for (int i = beg; i < end; ++i) {
        const int s = ss[i];              // wave-uniform, sequential
        const float4 mt = tbl[i];         // wave-uniform, sequential
        const int t = __float_as_int(mt.w);
        if (s != cur) {
            if (cur >= 0) {
                atomicAdd(&out[cur * 64 + lane], accS);
                const int bo = N * 64 + cur * 192 + lane;
                atomicAdd(&out[bo], accV0);
                atomicAdd(&out[bo + 64], accV1);
                atomicAdd(&out[bo + 128], accV2);
            }
            cur = s;
            accS = accV0 = accV1 = accV2 = 0.f;
            const float* gp = GS + (size_t)s * 256 + lane;
            gs0 = gp[0]; gs1 = gp[64]; gs2 = gp[128]; gs3 = gp[192];
        }
        const float* gd = GD + (size_t)t * 256 + lane;
        const float b0 = gd[0], b1 = gd[64], b2 = gd[128], b3 = gd[192];
        const float z0v = z0g[t * 64 + lane];
        const float za = z1g[t * 192 + lane];
        const float zb = z1g[t * 192 + 64 + lane];
        const float zc = z1g[t * 192 + 128 + lane];
        const float r0 = mt.x, r1 = mt.y, r2 = mt.z;

        float g0 = gs0 + b0 + bl0;
        float g1 = gs1 + b1 + bl1;
        float g2 = gs2 + b2 + bl2;
        float g3 = gs3 + b3 + bl3;

        const float d = sqrtf(r0 * r0 + r1 * r1 + r2 * r2);
        #pragma unroll
        for (int m = 0; m < 8; ++m) {
            const float mu = 0.28571428571f * (float)m;   // linspace(0, 2, 8)
            const float tt = (d - mu) * 4.0f;             // / sigma, sigma = 0.25
            const float rm = __expf(-tt * tt);
            const float* wq = &sWe[(m << 8) + lane];
            g0 += rm * wq[0];
            g1 += rm * wq[64];
            g2 += rm * wq[128];
            g3 += rm * wq[192];
        }

        const float v0 = r0 * 3.5f, v1 = r1 * 3.5f, v2 = r2 * 3.5f;
        const float inv = rsqrtf(1.0f + v0 * v0 + v1 * v1 + v2 * v2);
        const float h0 = v0 * inv, h1 = v1 * inv, h2 = v2 * inv;
        const float uu = h0 * za + h1 * zb + h2 * zc;

        accS  += g0 * z0v + g1 * uu;
        accV0 += g2 * za + g3 * h0 * z0v;
        accV1 += g2 * zb + g3 * h1 * z0v;
        accV2 += g2 * zc + g3 * h2 * z0v;
    }
    // final flush
    atomicAdd(&out[cur * 64 + lane], accS);
    const int bo = N * 64 + cur * 192 + lane;
    atomicAdd(&out[bo], accV0);
    atomicAdd(&out[bo + 64], accV1);
    atomicAdd(&out[bo + 128], accV2);
}

// ---------------------------------------------------------------- edge kernel (fast, fallback)
__global__ __launch_bounds__(256, 8) void edge_fast_k(
    const int* __restrict__ src, const int* __restrict__ dst,
    const float* __restrict__ r_ij, const float* __restrict__ z0g,
    const float* __restrict__ z1g, const float* __restrict__ GS,
    const float* __restrict__ GD, const float* __restrict__ WeG,
    const float* __restrict__ ball, float* __restrict__ out, int N, int E) {
    __shared__ float sWe[2048];
    __shared__ float sBall[256];
    __shared__ int sFl[2];

    if (threadIdx.x == 0) {
        const u32* ps = (const u32*)src;
        const u32* pd = (const u32*)dst;
        int s64 = 1, d64 = 1;
        for (int i = 1; i < 128; i += 2) {
            if (ps[i] != 0u) s64 = 0;
            if (pd[i] != 0u) d64 = 0;
        }
        sFl[0] = s64;
        sFl[1] = d64;
    }
    for (int i = threadIdx.x; i < 2048; i += 256) sWe[i] = WeG[i];
    sBall[threadIdx.x] = ball[threadIdx.x];
    __syncthreads();

    const int wid = threadIdx.x >> 6, lane = threadIdx.x & 63;
    const int i64s = sFl[0], i64d = sFl[1];

    for (int e = blockIdx.x * 4 + wid; e < E; e += gridDim.x * 4) {
        const int s = i64s ? src[2 * e] : src[e];
        const int t = i64d ? dst[2 * e] : dst[e];
        if (s < 0 || s >= N || t < 0 || t >= N) continue;

        const float* gs = GS + (size_t)s * 256 + lane;
        const float* gd = GD + (size_t)t * 256 + lane;
        const float a0 = gs[0], a1 = gs[64], a2 = gs[128], a3 = gs[192];
        const float b0 = gd[0], b1 = gd[64], b2 = gd[128], b3 = gd[192];
        const float z0v = z0g[t * 64 + lane];
        const float za = z1g[t * 192 + lane];
        const float zb = z1g[t * 192 + 64 + lane];
        const float zc = z1g[t * 192 + 128 + lane];
        const float r0 = r_ij[e * 3 + 0];
        const float r1 = r_ij[e * 3 + 1];
        const float r2 = r_ij[e * 3 + 2];

        float g0 = a0 + b0 + sBall[lane];
        float g1 = a1 + b1 + sBall[64 + lane];
        float g2 = a2 + b2 + sBall[128 + lane];
        float g3 = a3 + b3 + sBall[192 + lane];

        const float d = sqrtf(r0 * r0 + r1 * r1 + r2 * r2);
        #pragma unroll
        for (int m = 0; m < 8; ++m) {
            const float mu = 0.28571428571f * (float)m;
            const float tt = (d - mu) * 4.0f;
            const float rm = __expf(-tt * tt);
            const float* wq = &sWe[(m << 8) + lane];
            g0 += rm * wq[0];
            g1 += rm * wq[64];
            g2 += rm * wq[128];
            g3 += rm * wq[192];
        }

        const float v0 = r0 * 3.5f, v1 = r1 * 3.5f, v2 = r2 * 3.5f;
        const float inv = rsqrtf(1.0f + v0 * v0 + v1 * v1 + v2 * v2);
        const float h0 = v0 * inv, h1 = v1 * inv, h2 = v2 * inv;
        const float uu = h0 * za + h1 * zb + h2 * zc;

        const float smsg = g0 * z0v + g1 * uu;
        const float vm0 = g2 * za + g3 * h0 * z0v;
        const float vm1 = g2 * zb + g3 * h1 * z0v;
        const float vm2 = g2 * zc + g3 * h2 * z0v;

        atomicAdd(&out[s * 64 + lane], smsg);
        const int bo = N * 64 + s * 192 + lane;
        atomicAdd(&out[bo], vm0);
        atomicAdd(&out[bo + 64], vm1);
        atomicAdd(&out[bo + 128], vm2);
    }
}

// ---------------------------------------------------------------- node epilogue v2
// In place: out0[n] = S0[n] @ Ws ; out1[n][i] = V[n][i] @ Wv. 2 nodes/round.
__global__ __launch_bounds__(256) void nodepost2_k(
    float* __restrict__ out, const float* __restrict__ Ws,
    const float* __restrict__ Wv, int N) {
    __shared__ float sWs[4096];
    __shared__ float sWv[4096];
    __shared__ __align__(16) float sRow[2][256];
    for (int i = threadIdx.x; i < 4096; i += 256) {
        sWs[i] = Ws[i];
        sWv[i] = Wv[i];
    }
    __syncthreads();
    const int j = threadIdx.x;
    const int part = j >> 6;       // 0: scalar, 1..3: vector components
    const int col = j & 63;
    const int pj = j - 64;
    const float* W = (part == 0) ? sWs : sWv;
    for (int n0 = blockIdx.x * 2; n0 < N; n0 += gridDim.x * 2) {
        const int n1 = n0 + 1;
        const bool has1 = n1 < N;
        sRow[0][j] = (part == 0) ? out[n0 * 64 + j] : out[N * 64 + n0 * 192 + pj];
        if (has1)
            sRow[1][j] = (part == 0) ? out[n1 * 64 + j] : out[N * 64 + n1 * 192 + pj];
        __syncthreads();
        float a0 = 0.f, a1 = 0.f;
        #pragma unroll
        for (int k4 = 0; k4 < 16; ++k4) {
            const float4 rA = *(const float4*)&sRow[0][part * 64 + 4 * k4];
            const float4 rB = *(const float4*)&sRow[1][part * 64 + 4 * k4];
            const float w0 = W[(4 * k4 + 0) * 64 + col];
            const float w1 = W[(4 * k4 + 1) * 64 + col];
            const float w2 = W[(4 * k4 + 2) * 64 + col];
            const float w3 = W[(4 * k4 + 3) * 64 + col];
            a0 += rA.x * w0 + rA.y * w1 + rA.z * w2 + rA.w * w3;
            a1 += rB.x * w0 + rB.y * w1 + rB.z * w2 + rB.w * w3;
        }
        __syncthreads();
        if (part == 0) out[n0 * 64 + j] = a0;
        else out[N * 64 + n0 * 192 + pj] = a0;
        if (has1) {
            if (part == 0) out[n1 * 64 + j] = a1;
            else out[N * 64 + n1 * 192 + pj] = a1;
        }
    }
}

// ---------------------------------------------------------------- full fallback
__global__ __launch_bounds__(512, 1) void edge_k(
    const int* __restrict__ src, const int* __restrict__ dst,
    const float* __restrict__ r_ij, const float* __restrict__ z0g,
    const float* __restrict__ z1g, const float* __restrict__ emb,
    const float* __restrict__ Wenc, const float* __restrict__ benc,
    const float* __restrict__ Wsrc, const float* __restrict__ bsrc,
    const float* __restrict__ Wdst, const float* __restrict__ bdst,
    const float* __restrict__ Wgate, const float* __restrict__ bgate,
    const float* __restrict__ Ws, const float* __restrict__ Wv,
    float* __restrict__ out, int N, int E)
{
    __shared__ float sWsrc[4096];
    __shared__ float sWdst[4096];
    __shared__ float sWg[16384];
    __shared__ float sWs[4096];
    __shared__ float sWv[4096];
    __shared__ float sWe[512];
    __shared__ float sB[64];
    __shared__ float sBg[256];
    __shared__ int sFl[2];

    if (threadIdx.x == 0) {
        const u32* ps = (const u32*)src;
        const u32* pd = (const u32*)dst;
        int s64 = 1, d64 = 1;
        for (int i = 1; i < 128; i += 2) {
            if (ps[i] != 0u) s64 = 0;
            if (pd[i] != 0u) d64 = 0;
        }
        sFl[0] = s64;
        sFl[1] = d64;
    }
    for (int i = threadIdx.x; i < 4096; i += 512) {
        sWsrc[i] = Wsrc[i];
        sWdst[i] = Wdst[i];
        sWs[i] = Ws[i];
        sWv[i] = Wv[i];
    }
    for (int i = threadIdx.x; i < 16384; i += 512) sWg[i] = Wgate[i];
    for (int i = threadIdx.x; i < 512; i += 512) sWe[i] = Wenc[i];
    if (threadIdx.x < 64)
        sB[threadIdx.x] = benc[threadIdx.x] + bsrc[threadIdx.x] + bdst[threadIdx.x];
    if (threadIdx.x < 256) sBg[threadIdx.x] = bgate[threadIdx.x];
    __syncthreads();

    const int wid = threadIdx.x >> 6, lane = threadIdx.x & 63;
    const int i64s = sFl[0], i64d = sFl[1];

    for (int e = blockIdx.x * 8 + wid; e < E; e += gridDim.x * 8) {
        const int s = i64s ? src[2 * e] : src[e];
        const int t = i64d ? dst[2 * e] : dst[e];
        if (s < 0 || s >= N || t < 0 || t >= N) continue;

        const float es = emb[s * 64 + lane];
        const float et = emb[t * 64 + lane];
        float de = sB[lane];
        #pragma unroll 8
        for (int k = 0; k < 64; ++k) {
            de += __shfl(es, k, 64) * sWsrc[(k << 6) + lane];
            de += __shfl(et, k, 64) * sWdst[(k << 6) + lane];
        }
        const float r0 = r_ij[e * 3 + 0];
        const float r1 = r_ij[e * 3 + 1];
        const float r2 = r_ij[e * 3 + 2];
        const float d = sqrtf(r0 * r0 + r1 * r1 + r2 * r2);
        #pragma unroll
        for (int m = 0; m < 8; ++m) {
            const float mu = (2.0f / 7.0f) * (float)m;
            const float tt = (d - mu) * 4.0f;
            de += __expf(-tt * tt) * sWe[m * 64 + lane];
        }

        const float v0 = r0 * 3.5f, v1 = r1 * 3.5f, v2 = r2 * 3.5f;
        const float inv = rsqrtf(1.0f + v0 * v0 + v1 * v1 + v2 * v2);
        const float h0 = v0 * inv, h1 = v1 * inv, h2 = v2 * inv;

        const float z0v = z0g[t * 64 + lane];
        const float za = z1g[t * 192 + lane];
        const float zb = z1g[t * 192 + 64 + lane];
        const float zc = z1g[t * 192 + 128 + lane];
        const float uu = h0 * za + h1 * zb + h2 * zc;

        float g0 = sBg[lane], g1 = sBg[64 + lane], g2 = sBg[128 + lane], g3 = sBg[192 + lane];
        #pragma unroll 8
        for (int k = 0; k < 64; ++k) {
            const float dk = __shfl(de, k, 64);
            const float* w = &sWg[(k << 8) + lane];
            g0 += dk * w[0];
            g1 += dk * w[64];
            g2 += dk * w[128];
            g3 += dk * w[192];
        }

        const float smsg = g0 * z0v + g1 * uu;
        const float vm0 = g2 * za + g3 * h0 * z0v;
        const float vm1 = g2 * zb + g3 * h1 * z0v;
        const float vm2 = g2 * zc + g3 * h2 * z0v;

        float p0 = 0.f, q0 = 0.f, q1 = 0.f, q2 = 0.f;
        #pragma unroll 8
        for (int k = 0; k < 64; ++k) {
            const float sk = __shfl(smsg, k, 64);
            const float a = __shfl(vm0, k, 64);
            const float b = __shfl(vm1, k, 64);
            const float c = __shfl(vm2, k, 64);
            p0 += sk * sWs[(k << 6) + lane];
            const float wv = sWv[(k << 6) + lane];
            q0 += a * wv;
            q1 += b * wv;
            q2 += c * wv;
        }

        atomicAdd(&out[s * 64 + lane], p0);
        const int b1 = N * 64 + s * 192 + lane;
        atomicAdd(&out[b1], q0);
        atomicAdd(&out[b1 + 64], q1);
        atomicAdd(&out[b1 + 128], q2);
    }
}

extern "C" void kernel_launch(void* const* d_in, const int* in_sizes, int n_in,
                              void* d_out, int out_size, void* d_ws, size_t ws_size,
                              hipStream_t stream) {
    const int* src = (const int*)d_in[0];
    const int* dst = (const int*)d_in[1];
    const float* r_ij = (const float*)d_in[2];
    const float* z0g  = (const float*)d_in[3];
    const float* z1g  = (const float*)d_in[4];
    const float* emb  = (const float*)d_in[5];
    const float* Wenc = (const float*)d_in[6];
    const float* benc = (const float*)d_in[7];
    const float* Wsrc = (const float*)d_in[8];
    const float* bsrc = (const float*)d_in[9];
    const float* Wdst = (const float*)d_in[10];
    const float* bdst = (const float*)d_in[11];
    const float* Wgate = (const float*)d_in[12];
    const float* bgate = (const float*)d_in[13];
    const float* Ws = (const float*)d_in[14];
    const float* Wv = (const float*)d_in[15];

    const int N = out_size / 256;                    // out0 N*64 + out1 N*192
    int E = in_sizes[0];
    if (in_sizes[2] / 3 < E) E = in_sizes[2] / 3;    // robustness

    zero_k<<<2048, 256, 0, stream>>>((float*)d_out, out_size);

    float* ws = (float*)d_ws;
    const size_t gsgd = 2u * (size_t)N * 256u;
    const size_t Np = ((size_t)N + 3u) & ~3ull;      // padded for alignment
    const size_t Ep = ((size_t)E + 3u) & ~3ull;
    const size_t needGSGD = ((size_t)WS_GS + gsgd) * sizeof(float);
    const size_t needCSR  = ((size_t)WS_GS + gsgd + Np + Ep + 4u * (size_t)E + 64u) * sizeof(float);

    if (ws != nullptr && ws_size >= needGSGD) {
        compose_k<<<73, 256, 0, stream>>>(Wsrc, Wdst, Wenc, benc, bsrc, bdst,
                                          Wgate, bgate, ws);
        float* GS = ws + WS_GS;
        float* GD = GS + (size_t)N * 256;
        nodepre2_k<<<512, 256, 0, stream>>>(emb, ws + WS_WSG, GS, N);
        nodepre2_k<<<512, 256, 0, stream>>>(emb, ws + WS_WDG, GD, N);

        if (ws_size >= needCSR) {
            int* cnt = (int*)(GD + (size_t)N * 256);
            int* ss  = cnt + Np;
            float4* tbl = (float4*)(ss + Ep);
            int* etot = (int*)ws + WS_ETOT;
            zero_k<<<64, 256, 0, stream>>>((float*)cnt, N);
            count_k<<<1024, 256, 0, stream>>>(src, dst, cnt, N, E);
            scan_k<<<1, 1024, 0, stream>>>(cnt, etot, N);
            fill_k<<<1024, 256, 0, stream>>>(src, dst, r_ij, cnt, ss, tbl, N, E);
            edge_sorted_k<<<2048, 256, 0, stream>>>(GS, GD, z0g, z1g, ss, tbl,
                                                    ws + WS_WEG, ws + WS_BALL,
                                                    etot, (float*)d_out, N);
        } else {
            edge_fast_k<<<2048, 256, 0, stream>>>(src, dst, r_ij, z0g, z1g, GS, GD,
                                                  ws + WS_WEG, ws + WS_BALL,
                                                  (float*)d_out, N, E);
        }
        nodepost2_k<<<2048, 256, 0, stream>>>((float*)d_out, Ws, Wv, N);
    } else {
        edge_k<<<2048, 512, 0, stream>>>(src, dst, r_ij, z0g, z1g, emb, Wenc, benc,
                                         Wsrc, bsrc, Wdst, bdst, Wgate, bgate, Ws, Wv,
                                         (float*)d_out, N, E);
    }
}

// Round 3
// 1559.107 us; speedup vs baseline: 1.0383x; 1.0383x over previous
//
#include <hip/hip_runtime.h>

typedef unsigned int u32;

// ---- workspace layout (float offsets) ----
#define WS_WSG   0        // 64x256: Wsrc @ Wgate   [k][j]
#define WS_WDG   16384    // 64x256: Wdst @ Wgate   [k][j]
#define WS_WEG   32768    // 8x256 : Wenc @ Wgate   [m][j]
#define WS_BALL  34816    // 256   : (benc+bsrc+bdst) @ Wgate + bgate
#define WS_GS    35328    // N x 256 (GS), then N x 256 (GD)

// ---------------------------------------------------------------- zero out
__global__ void zero_k(float* p, int n) {
    int i = blockIdx.x * blockDim.x + threadIdx.x;
    int st = gridDim.x * blockDim.x;
    for (; i < n; i += st) p[i] = 0.0f;
}

// ---------------------------------------------------------------- compose weights
// 73 blocks x 256 threads. Rows 0..63: WsG & WdG; 64..71: WeG; 72: bias row.
__global__ void compose_k(const float* __restrict__ Wsrc, const float* __restrict__ Wdst,
                          const float* __restrict__ Wenc, const float* __restrict__ benc,
                          const float* __restrict__ bsrc, const float* __restrict__ bdst,
                          const float* __restrict__ Wgate, const float* __restrict__ bgate,
                          float* __restrict__ ws) {
    const int j = threadIdx.x;           // 0..255
    const int r = blockIdx.x;            // 0..72
    if (r < 64) {
        float a = 0.f, b = 0.f;
        for (int c = 0; c < 64; ++c) {
            const float wg = Wgate[c * 256 + j];
            a += Wsrc[r * 64 + c] * wg;
            b += Wdst[r * 64 + c] * wg;
        }
        ws[WS_WSG + r * 256 + j] = a;
        ws[WS_WDG + r * 256 + j] = b;
    } else if (r < 72) {
        const int m = r - 64;
        float a = 0.f;
        for (int c = 0; c < 64; ++c) a += Wenc[m * 64 + c] * Wgate[c * 256 + j];
        ws[WS_WEG + m * 256 + j] = a;
    } else {
        float a = bgate[j];
        for (int c = 0; c < 64; ++c)
            a += (benc[c] + bsrc[c] + bdst[c]) * Wgate[c * 256 + j];
        ws[WS_BALL + j] = a;
    }
}

// ---------------------------------------------------------------- node precompute
// G[n][j] = sum_k emb[n][k] * Wg[k][j]. 256 threads, 4 nodes/iter,
// float4 broadcast reads of emb; 64KB LDS -> 2 blocks/CU.  (verified round 2)
__global__ __launch_bounds__(256, 2) void nodepre2_k(
    const float* __restrict__ emb, const float* __restrict__ Wg,
    float* __restrict__ G, int N) {
    __shared__ float sW[16384];                  // [k][j], 64 KB
    __shared__ __align__(16) float sEm[256];     // 4 node rows
    for (int i = threadIdx.x * 4; i < 16384; i += 1024)
        *(float4*)&sW[i] = *(const float4*)&Wg[i];
    const int j = threadIdx.x;
    const int ngr = (N + 3) >> 2;
    for (int g = blockIdx.x; g < ngr; g += gridDim.x) {
        const int n0 = g * 4;
        const int nn = n0 + (j >> 6);
        sEm[j] = (nn < N) ? emb[nn * 64 + (j & 63)] : 0.f;
        __syncthreads();
        float a0 = 0.f, a1 = 0.f, a2 = 0.f, a3 = 0.f;
        #pragma unroll
        for (int k4 = 0; k4 < 16; ++k4) {
            const float4 e0 = *(const float4*)&sEm[4 * k4];
            const float4 e1 = *(const float4*)&sEm[64 + 4 * k4];
            const float4 e2 = *(const float4*)&sEm[128 + 4 * k4];
            const float4 e3 = *(const float4*)&sEm[192 + 4 * k4];
            const float w0 = sW[(4 * k4 + 0) * 256 + j];
            const float w1 = sW[(4 * k4 + 1) * 256 + j];
            const float w2 = sW[(4 * k4 + 2) * 256 + j];
            const float w3 = sW[(4 * k4 + 3) * 256 + j];
            a0 += e0.x * w0 + e0.y * w1 + e0.z * w2 + e0.w * w3;
            a1 += e1.x * w0 + e1.y * w1 + e1.z * w2 + e1.w * w3;
            a2 += e2.x * w0 + e2.y * w1 + e2.z * w2 + e2.w * w3;
            a3 += e3.x * w0 + e3.y * w1 + e3.z * w2 + e3.w * w3;
        }
        __syncthreads();
        if (n0 < N)     G[(size_t)n0 * 256 + j] = a0;
        if (n0 + 1 < N) G[(size_t)(n0 + 1) * 256 + j] = a1;
        if (n0 + 2 < N) G[(size_t)(n0 + 2) * 256 + j] = a2;
        if (n0 + 3 < N) G[(size_t)(n0 + 3) * 256 + j] = a3;
    }
}

// ---------------------------------------------------------------- edge kernel (pipelined)
// One wave per contiguous edge chunk. 2-deep software pipeline: issue edge
// i+1's gathers before consuming edge i (double MLP per wave). Atomics are
// fire-and-forget so only gather latency is on the critical path.
struct ER {
    int s, t;
    float ok;
    float r0, r1, r2;
    float a0, a1, a2, a3;     // GS row
    float b0, b1, b2, b3;     // GD row
    float z0, za, zb, zc;     // z0_j, z1_j rows
};

__device__ __forceinline__ ER load_edge(
    int e, int lane, int i64s, int i64d, int N,
    const int* __restrict__ src, const int* __restrict__ dst,
    const float* __restrict__ r_ij, const float* __restrict__ GS,
    const float* __restrict__ GD, const float* __restrict__ z0g,
    const float* __restrict__ z1g) {
    ER x;
    int s = i64s ? src[2 * e] : src[e];
    int t = i64d ? dst[2 * e] : dst[e];
    x.ok = 1.f;
    if (s < 0 || s >= N) { s = 0; x.ok = 0.f; }
    if (t < 0 || t >= N) { t = 0; x.ok = 0.f; }
    x.s = s; x.t = t;
    x.r0 = r_ij[e * 3 + 0];
    x.r1 = r_ij[e * 3 + 1];
    x.r2 = r_ij[e * 3 + 2];
    const float* gp = GS + (size_t)s * 256 + lane;
    x.a0 = gp[0]; x.a1 = gp[64]; x.a2 = gp[128]; x.a3 = gp[192];
    const float* gd = GD + (size_t)t * 256 + lane;
    x.b0 = gd[0]; x.b1 = gd[64]; x.b2 = gd[128]; x.b3 = gd[192];
    x.z0 = z0g[t * 64 + lane];
    const float* zp = z1g + t * 192 + lane;
    x.za = zp[0]; x.zb = zp[64]; x.zc = zp[128];
    return x;
}

__device__ __forceinline__ void consume_edge(
    const ER& x, int lane, int N,
    const float* __restrict__ sWe,
    float bl0, float bl1, float bl2, float bl3,
    float* __restrict__ out) {
    float g0 = x.a0 + x.b0 + bl0;
    float g1 = x.a1 + x.b1 + bl1;
    float g2 = x.a2 + x.b2 + bl2;
    float g3 = x.a3 + x.b3 + bl3;

    const float d = sqrtf(x.r0 * x.r0 + x.r1 * x.r1 + x.r2 * x.r2);
    #pragma unroll
    for (int m = 0; m < 8; ++m) {
        const float mu = 0.28571428571f * (float)m;   // linspace(0, 2, 8)
        const float tt = (d - mu) * 4.0f;             // / sigma, sigma = 0.25
        const float rm = __expf(-tt * tt);
        const float* wq = &sWe[(m << 8) + lane];
        g0 += rm * wq[0];
        g1 += rm * wq[64];
        g2 += rm * wq[128];
        g3 += rm * wq[192];
    }

    const float v0 = x.r0 * 3.5f, v1 = x.r1 * 3.5f, v2 = x.r2 * 3.5f;
    const float inv = rsqrtf(1.0f + v0 * v0 + v1 * v1 + v2 * v2);
    const float h0 = v0 * inv, h1 = v1 * inv, h2 = v2 * inv;
    const float uu = h0 * x.za + h1 * x.zb + h2 * x.zc;

    const float smsg = (g0 * x.z0 + g1 * uu) * x.ok;
    const float vm0 = (g2 * x.za + g3 * h0 * x.z0) * x.ok;
    const float vm1 = (g2 * x.zb + g3 * h1 * x.z0) * x.ok;
    const float vm2 = (g2 * x.zc + g3 * h2 * x.z0) * x.ok;

    atomicAdd(&out[x.s * 64 + lane], smsg);
    const int bo = N * 64 + x.s * 192 + lane;
    atomicAdd(&out[bo], vm0);
    atomicAdd(&out[bo + 64], vm1);
    atomicAdd(&out[bo + 128], vm2);
}

__global__ __launch_bounds__(256, 8) void edge_pipe_k(
    const int* __restrict__ src, const int* __restrict__ dst,
    const float* __restrict__ r_ij, const float* __restrict__ z0g,
    const float* __restrict__ z1g, const float* __restrict__ GS,
    const float* __restrict__ GD, const float* __restrict__ WeG,
    const float* __restrict__ ball, float* __restrict__ out, int N, int E) {
    __shared__ float sWe[2048];   // 8 KB
    __shared__ float sBall[256];  // 1 KB
    __shared__ int sFl[2];

    if (threadIdx.x == 0) {
        const u32* ps = (const u32*)src;
        const u32* pd = (const u32*)dst;
        int s64 = 1, d64 = 1;
        for (int i = 1; i < 128; i += 2) {
            if (ps[i] != 0u) s64 = 0;
            if (pd[i] != 0u) d64 = 0;
        }
        sFl[0] = s64;
        sFl[1] = d64;
    }
    for (int i = threadIdx.x; i < 2048; i += 256) sWe[i] = WeG[i];
    sBall[threadIdx.x] = ball[threadIdx.x];
    __syncthreads();

    const int wid = threadIdx.x >> 6, lane = threadIdx.x & 63;
    const int i64s = sFl[0], i64d = sFl[1];

    const int gw = blockIdx.x * 4 + wid;
    const int nw = gridDim.x * 4;
    const int chunk = (E + nw - 1) / nw;
    const int beg = gw * chunk;
    int end = beg + chunk; if (end > E) end = E;
    if (beg >= end) return;

    const float bl0 = sBall[lane], bl1 = sBall[64 + lane];
    const float bl2 = sBall[128 + lane], bl3 = sBall[192 + lane];

    ER cur = load_edge(beg, lane, i64s, i64d, N, src, dst, r_ij, GS, GD, z0g, z1g);
    for (int i = beg; i + 1 < end; ++i) {
        ER nxt = load_edge(i + 1, lane, i64s, i64d, N, src, dst, r_ij, GS, GD, z0g, z1g);
        consume_edge(cur, lane, N, sWe, bl0, bl1, bl2, bl3, out);
        cur = nxt;
    }
    consume_edge(cur, lane, N, sWe, bl0, bl1, bl2, bl3, out);
}

// ---------------------------------------------------------------- node epilogue
// In place: out0[n] = S0[n] @ Ws ; out1[n][i] = V[n][i] @ Wv. 2 nodes/round.
// (verified round 2)
__global__ __launch_bounds__(256) void nodepost2_k(
    float* __restrict__ out, const float* __restrict__ Ws,
    const float* __restrict__ Wv, int N) {
    __shared__ float sWs[4096];
    __shared__ float sWv[4096];
    __shared__ __align__(16) float sRow[2][256];
    for (int i = threadIdx.x; i < 4096; i += 256) {
        sWs[i] = Ws[i];
        sWv[i] = Wv[i];
    }
    __syncthreads();
    const int j = threadIdx.x;
    const int part = j >> 6;       // 0: scalar, 1..3: vector components
    const int col = j & 63;
    const int pj = j - 64;
    const float* W = (part == 0) ? sWs : sWv;
    for (int n0 = blockIdx.x * 2; n0 < N; n0 += gridDim.x * 2) {
        const int n1 = n0 + 1;
        const bool has1 = n1 < N;
        sRow[0][j] = (part == 0) ? out[n0 * 64 + j] : out[N * 64 + n0 * 192 + pj];
        if (has1)
            sRow[1][j] = (part == 0) ? out[n1 * 64 + j] : out[N * 64 + n1 * 192 + pj];
        __syncthreads();
        float a0 = 0.f, a1 = 0.f;
        #pragma unroll
        for (int k4 = 0; k4 < 16; ++k4) {
            const float4 rA = *(const float4*)&sRow[0][part * 64 + 4 * k4];
            const float4 rB = *(const float4*)&sRow[1][part * 64 + 4 * k4];
            const float w0 = W[(4 * k4 + 0) * 64 + col];
            const float w1 = W[(4 * k4 + 1) * 64 + col];
            const float w2 = W[(4 * k4 + 2) * 64 + col];
            const float w3 = W[(4 * k4 + 3) * 64 + col];
            a0 += rA.x * w0 + rA.y * w1 + rA.z * w2 + rA.w * w3;
            a1 += rB.x * w0 + rB.y * w1 + rB.z * w2 + rB.w * w3;
        }
        __syncthreads();
        if (part == 0) out[n0 * 64 + j] = a0;
        else out[N * 64 + n0 * 192 + pj] = a0;
        if (has1) {
            if (part == 0) out[n1 * 64 + j] = a1;
            else out[N * 64 + n1 * 192 + pj] = a1;
        }
    }
}

// ---------------------------------------------------------------- full fallback
__global__ __launch_bounds__(512, 1) void edge_k(
    const int* __restrict__ src, const int* __restrict__ dst,
    const float* __restrict__ r_ij, const float* __restrict__ z0g,
    const float* __restrict__ z1g, const float* __restrict__ emb,
    const float* __restrict__ Wenc, const float* __restrict__ benc,
    const float* __restrict__ Wsrc, const float* __restrict__ bsrc,
    const float* __restrict__ Wdst, const float* __restrict__ bdst,
    const float* __restrict__ Wgate, const float* __restrict__ bgate,
    const float* __restrict__ Ws, const float* __restrict__ Wv,
    float* __restrict__ out, int N, int E)
{
    __shared__ float sWsrc[4096];
    __shared__ float sWdst[4096];
    __shared__ float sWg[16384];
    __shared__ float sWs[4096];
    __shared__ float sWv[4096];
    __shared__ float sWe[512];
    __shared__ float sB[64];
    __shared__ float sBg[256];
    __shared__ int sFl[2];

    if (threadIdx.x == 0) {
        const u32* ps = (const u32*)src;
        const u32* pd = (const u32*)dst;
        int s64 = 1, d64 = 1;
        for (int i = 1; i < 128; i += 2) {
            if (ps[i] != 0u) s64 = 0;
            if (pd[i] != 0u) d64 = 0;
        }
        sFl[0] = s64;
        sFl[1] = d64;
    }
    for (int i = threadIdx.x; i < 4096; i += 512) {
        sWsrc[i] = Wsrc[i];
        sWdst[i] = Wdst[i];
        sWs[i] = Ws[i];
        sWv[i] = Wv[i];
    }
    for (int i = threadIdx.x; i < 16384; i += 512) sWg[i] = Wgate[i];
    for (int i = threadIdx.x; i < 512; i += 512) sWe[i] = Wenc[i];
    if (threadIdx.x < 64)
        sB[threadIdx.x] = benc[threadIdx.x] + bsrc[threadIdx.x] + bdst[threadIdx.x];
    if (threadIdx.x < 256) sBg[threadIdx.x] = bgate[threadIdx.x];
    __syncthreads();

    const int wid = threadIdx.x >> 6, lane = threadIdx.x & 63;
    const int i64s = sFl[0], i64d = sFl[1];

    for (int e = blockIdx.x * 8 + wid; e < E; e += gridDim.x * 8) {
        const int s = i64s ? src[2 * e] : src[e];
        const int t = i64d ? dst[2 * e] : dst[e];
        if (s < 0 || s >= N || t < 0 || t >= N) continue;

        const float es = emb[s * 64 + lane];
        const float et = emb[t * 64 + lane];
        float de = sB[lane];
        #pragma unroll 8
        for (int k = 0; k < 64; ++k) {
            de += __shfl(es, k, 64) * sWsrc[(k << 6) + lane];
            de += __shfl(et, k, 64) * sWdst[(k << 6) + lane];
        }
        const float r0 = r_ij[e * 3 + 0];
        const float r1 = r_ij[e * 3 + 1];
        const float r2 = r_ij[e * 3 + 2];
        const float d = sqrtf(r0 * r0 + r1 * r1 + r2 * r2);
        #pragma unroll
        for (int m = 0; m < 8; ++m) {
            const float mu = (2.0f / 7.0f) * (float)m;
            const float tt = (d - mu) * 4.0f;
            de += __expf(-tt * tt) * sWe[m * 64 + lane];
        }

        const float v0 = r0 * 3.5f, v1 = r1 * 3.5f, v2 = r2 * 3.5f;
        const float inv = rsqrtf(1.0f + v0 * v0 + v1 * v1 + v2 * v2);
        const float h0 = v0 * inv, h1 = v1 * inv, h2 = v2 * inv;

        const float z0v = z0g[t * 64 + lane];
        const float za = z1g[t * 192 + lane];
        const float zb = z1g[t * 192 + 64 + lane];
        const float zc = z1g[t * 192 + 128 + lane];
        const float uu = h0 * za + h1 * zb + h2 * zc;

        float g0 = sBg[lane], g1 = sBg[64 + lane], g2 = sBg[128 + lane], g3 = sBg[192 + lane];
        #pragma unroll 8
        for (int k = 0; k < 64; ++k) {
            const float dk = __shfl(de, k, 64);
            const float* w = &sWg[(k << 8) + lane];
            g0 += dk * w[0];
            g1 += dk * w[64];
            g2 += dk * w[128];
            g3 += dk * w[192];
        }

        const float smsg = g0 * z0v + g1 * uu;
        const float vm0 = g2 * za + g3 * h0 * z0v;
        const float vm1 = g2 * zb + g3 * h1 * z0v;
        const float vm2 = g2 * zc + g3 * h2 * z0v;

        float p0 = 0.f, q0 = 0.f, q1 = 0.f, q2 = 0.f;
        #pragma unroll 8
        for (int k = 0; k < 64; ++k) {
            const float sk = __shfl(smsg, k, 64);
            const float a = __shfl(vm0, k, 64);
            const float b = __shfl(vm1, k, 64);
            const float c = __shfl(vm2, k, 64);
            p0 += sk * sWs[(k << 6) + lane];
            const float wv = sWv[(k << 6) + lane];
            q0 += a * wv;
            q1 += b * wv;
            q2 += c * wv;
        }

        atomicAdd(&out[s * 64 + lane], p0);
        const int b1 = N * 64 + s * 192 + lane;
        atomicAdd(&out[b1], q0);
        atomicAdd(&out[b1 + 64], q1);
        atomicAdd(&out[b1 + 128], q2);
    }
}

extern "C" void kernel_launch(void* const* d_in, const int* in_sizes, int n_in,
                              void* d_out, int out_size, void* d_ws, size_t ws_size,
                              hipStream_t stream) {
    const int* src = (const int*)d_in[0];
    const int* dst = (const int*)d_in[1];
    const float* r_ij = (const float*)d_in[2];
    const float* z0g  = (const float*)d_in[3];
    const float* z1g  = (const float*)d_in[4];
    const float* emb  = (const float*)d_in[5];
    const float* Wenc = (const float*)d_in[6];
    const float* benc = (const float*)d_in[7];
    const float* Wsrc = (const float*)d_in[8];
    const float* bsrc = (const float*)d_in[9];
    const float* Wdst = (const float*)d_in[10];
    const float* bdst = (const float*)d_in[11];
    const float* Wgate = (const float*)d_in[12];
    const float* bgate = (const float*)d_in[13];
    const float* Ws = (const float*)d_in[14];
    const float* Wv = (const float*)d_in[15];

    const int N = out_size / 256;                    // out0 N*64 + out1 N*192
    int E = in_sizes[0];
    if (in_sizes[2] / 3 < E) E = in_sizes[2] / 3;    // robustness

    zero_k<<<2048, 256, 0, stream>>>((float*)d_out, out_size);

    float* ws = (float*)d_ws;
    const size_t gsgd = 2u * (size_t)N * 256u;
    const size_t needGSGD = ((size_t)WS_GS + gsgd) * sizeof(float);

    if (ws != nullptr && ws_size >= needGSGD) {
        compose_k<<<73, 256, 0, stream>>>(Wsrc, Wdst, Wenc, benc, bsrc, bdst,
                                          Wgate, bgate, ws);
        float* GS = ws + WS_GS;
        float* GD = GS + (size_t)N * 256;
        nodepre2_k<<<512, 256, 0, stream>>>(emb, ws + WS_WSG, GS, N);
        nodepre2_k<<<512, 256, 0, stream>>>(emb, ws + WS_WDG, GD, N);
        edge_pipe_k<<<2048, 256, 0, stream>>>(src, dst, r_ij, z0g, z1g, GS, GD,
                                              ws + WS_WEG, ws + WS_BALL,
                                              (float*)d_out, N, E);
        nodepost2_k<<<2048, 256, 0, stream>>>((float*)d_out, Ws, Wv, N);
    } else {
        edge_k<<<2048, 512, 0, stream>>>(src, dst, r_ij, z0g, z1g, emb, Wenc, benc,
                                         Wsrc, bsrc, Wdst, bdst, Wgate, bgate, Ws, Wv,
                                         (float*)d_out, N, E);
    }
}

// Round 4
// 1291.197 us; speedup vs baseline: 1.2537x; 1.2075x over previous
//
#include <hip/hip_runtime.h>

typedef unsigned int u32;

// ---- workspace layout (float offsets) ----
#define WS_WSG   0        // 64x256: Wsrc @ Wgate   [k][j]
#define WS_WDG   16384    // 64x256: Wdst @ Wgate   [k][j]
#define WS_WEG   32768    // 8x256 : Wenc @ Wgate   [m][j]
#define WS_BALL  34816    // 256   : (benc+bsrc+bdst) @ Wgate + bgate
#define WS_GS    35328    // N x 256 (GS), then N x 256 (GD)

// ---------------------------------------------------------------- zero out
__global__ void zero_k(float* p, int n) {
    int i = blockIdx.x * blockDim.x + threadIdx.x;
    int st = gridDim.x * blockDim.x;
    for (; i < n; i += st) p[i] = 0.0f;
}

// ---------------------------------------------------------------- compose weights
// 73 blocks x 256 threads. Rows 0..63: WsG & WdG; 64..71: WeG; 72: bias row.
__global__ void compose_k(const float* __restrict__ Wsrc, const float* __restrict__ Wdst,
                          const float* __restrict__ Wenc, const float* __restrict__ benc,
                          const float* __restrict__ bsrc, const float* __restrict__ bdst,
                          const float* __restrict__ Wgate, const float* __restrict__ bgate,
                          float* __restrict__ ws) {
    const int j = threadIdx.x;           // 0..255
    const int r = blockIdx.x;            // 0..72
    if (r < 64) {
        float a = 0.f, b = 0.f;
        for (int c = 0; c < 64; ++c) {
            const float wg = Wgate[c * 256 + j];
            a += Wsrc[r * 64 + c] * wg;
            b += Wdst[r * 64 + c] * wg;
        }
        ws[WS_WSG + r * 256 + j] = a;
        ws[WS_WDG + r * 256 + j] = b;
    } else if (r < 72) {
        const int m = r - 64;
        float a = 0.f;
        for (int c = 0; c < 64; ++c) a += Wenc[m * 64 + c] * Wgate[c * 256 + j];
        ws[WS_WEG + m * 256 + j] = a;
    } else {
        float a = bgate[j];
        for (int c = 0; c < 64; ++c)
            a += (benc[c] + bsrc[c] + bdst[c]) * Wgate[c * 256 + j];
        ws[WS_BALL + j] = a;
    }
}

// ---------------------------------------------------------------- node precompute
// G[n][j] = sum_k emb[n][k] * Wg[k][j]. 256 threads, 4 nodes/iter,
// float4 broadcast reads of emb; 64KB LDS -> 2 blocks/CU.  (verified round 2)
__global__ __launch_bounds__(256, 2) void nodepre2_k(
    const float* __restrict__ emb, const float* __restrict__ Wg,
    float* __restrict__ G, int N) {
    __shared__ float sW[16384];                  // [k][j], 64 KB
    __shared__ __align__(16) float sEm[256];     // 4 node rows
    for (int i = threadIdx.x * 4; i < 16384; i += 1024)
        *(float4*)&sW[i] = *(const float4*)&Wg[i];
    const int j = threadIdx.x;
    const int ngr = (N + 3) >> 2;
    for (int g = blockIdx.x; g < ngr; g += gridDim.x) {
        const int n0 = g * 4;
        const int nn = n0 + (j >> 6);
        sEm[j] = (nn < N) ? emb[nn * 64 + (j & 63)] : 0.f;
        __syncthreads();
        float a0 = 0.f, a1 = 0.f, a2 = 0.f, a3 = 0.f;
        #pragma unroll
        for (int k4 = 0; k4 < 16; ++k4) {
            const float4 e0 = *(const float4*)&sEm[4 * k4];
            const float4 e1 = *(const float4*)&sEm[64 + 4 * k4];
            const float4 e2 = *(const float4*)&sEm[128 + 4 * k4];
            const float4 e3 = *(const float4*)&sEm[192 + 4 * k4];
            const float w0 = sW[(4 * k4 + 0) * 256 + j];
            const float w1 = sW[(4 * k4 + 1) * 256 + j];
            const float w2 = sW[(4 * k4 + 2) * 256 + j];
            const float w3 = sW[(4 * k4 + 3) * 256 + j];
            a0 += e0.x * w0 + e0.y * w1 + e0.z * w2 + e0.w * w3;
            a1 += e1.x * w0 + e1.y * w1 + e1.z * w2 + e1.w * w3;
            a2 += e2.x * w0 + e2.y * w1 + e2.z * w2 + e2.w * w3;
            a3 += e3.x * w0 + e3.y * w1 + e3.z * w2 + e3.w * w3;
        }
        __syncthreads();
        if (n0 < N)     G[(size_t)n0 * 256 + j] = a0;
        if (n0 + 1 < N) G[(size_t)(n0 + 1) * 256 + j] = a1;
        if (n0 + 2 < N) G[(size_t)(n0 + 2) * 256 + j] = a2;
        if (n0 + 3 < N) G[(size_t)(n0 + 3) * 256 + j] = a3;
    }
}

// ---------------------------------------------------------------- edge kernel (fast)
// EXACT round-1 structure: one wave per edge, STRIDED traversal (all in-flight
// waves share one contiguous edge window -> shared stream lines + gather
// working set fits per-XCD L2). Measured 443 us / 759 MB fetch / 500 MB write.
__global__ __launch_bounds__(256, 8) void edge_fast_k(
    const int* __restrict__ src, const int* __restrict__ dst,
    const float* __restrict__ r_ij, const float* __restrict__ z0g,
    const float* __restrict__ z1g, const float* __restrict__ GS,
    const float* __restrict__ GD, const float* __restrict__ WeG,
    const float* __restrict__ ball, float* __restrict__ out, int N, int E) {
    __shared__ float sWe[2048];   // 8 KB
    __shared__ float sBall[256];  // 1 KB
    __shared__ int sFl[2];

    if (threadIdx.x == 0) {
        const u32* ps = (const u32*)src;
        const u32* pd = (const u32*)dst;
        int s64 = 1, d64 = 1;
        for (int i = 1; i < 128; i += 2) {
            if (ps[i] != 0u) s64 = 0;
            if (pd[i] != 0u) d64 = 0;
        }
        sFl[0] = s64;
        sFl[1] = d64;
    }
    for (int i = threadIdx.x; i < 2048; i += 256) sWe[i] = WeG[i];
    sBall[threadIdx.x] = ball[threadIdx.x];
    __syncthreads();

    const int wid = threadIdx.x >> 6, lane = threadIdx.x & 63;
    const int i64s = sFl[0], i64d = sFl[1];

    for (int e = blockIdx.x * 4 + wid; e < E; e += gridDim.x * 4) {
        const int s = i64s ? src[2 * e] : src[e];
        const int t = i64d ? dst[2 * e] : dst[e];
        if (s < 0 || s >= N || t < 0 || t >= N) continue;

        // issue all gathers up front
        const float* gs = GS + (size_t)s * 256 + lane;
        const float* gd = GD + (size_t)t * 256 + lane;
        const float a0 = gs[0], a1 = gs[64], a2 = gs[128], a3 = gs[192];
        const float b0 = gd[0], b1 = gd[64], b2 = gd[128], b3 = gd[192];
        const float z0v = z0g[t * 64 + lane];
        const float za = z1g[t * 192 + lane];
        const float zb = z1g[t * 192 + 64 + lane];
        const float zc = z1g[t * 192 + 128 + lane];
        const float r0 = r_ij[e * 3 + 0];
        const float r1 = r_ij[e * 3 + 1];
        const float r2 = r_ij[e * 3 + 2];

        float g0 = a0 + b0 + sBall[lane];
        float g1 = a1 + b1 + sBall[64 + lane];
        float g2 = a2 + b2 + sBall[128 + lane];
        float g3 = a3 + b3 + sBall[192 + lane];

        const float d = sqrtf(r0 * r0 + r1 * r1 + r2 * r2);
        #pragma unroll
        for (int m = 0; m < 8; ++m) {
            const float mu = 0.28571428571f * (float)m;   // linspace(0, 2, 8)
            const float tt = (d - mu) * 4.0f;             // / sigma, sigma = 0.25
            const float rm = __expf(-tt * tt);
            const float* wq = &sWe[(m << 8) + lane];
            g0 += rm * wq[0];
            g1 += rm * wq[64];
            g2 += rm * wq[128];
            g3 += rm * wq[192];
        }

        // r_hat = v/sqrt(1+|v|^2), v = r_ij*3.5
        const float v0 = r0 * 3.5f, v1 = r1 * 3.5f, v2 = r2 * 3.5f;
        const float inv = rsqrtf(1.0f + v0 * v0 + v1 * v1 + v2 * v2);
        const float h0 = v0 * inv, h1 = v1 * inv, h2 = v2 * inv;
        const float uu = h0 * za + h1 * zb + h2 * zc;     // r_hat . z1_j

        const float smsg = g0 * z0v + g1 * uu;
        const float vm0 = g2 * za + g3 * h0 * z0v;
        const float vm1 = g2 * zb + g3 * h1 * z0v;
        const float vm2 = g2 * zc + g3 * h2 * z0v;

        atomicAdd(&out[s * 64 + lane], smsg);
        const int bo = N * 64 + s * 192 + lane;
        atomicAdd(&out[bo], vm0);
        atomicAdd(&out[bo + 64], vm1);
        atomicAdd(&out[bo + 128], vm2);
    }
}

// ---------------------------------------------------------------- node epilogue
// In place: out0[n] = S0[n] @ Ws ; out1[n][i] = V[n][i] @ Wv. 2 nodes/round.
// (verified round 2)
__global__ __launch_bounds__(256) void nodepost2_k(
    float* __restrict__ out, const float* __restrict__ Ws,
    const float* __restrict__ Wv, int N) {
    __shared__ float sWs[4096];
    __shared__ float sWv[4096];
    __shared__ __align__(16) float sRow[2][256];
    for (int i = threadIdx.x; i < 4096; i += 256) {
        sWs[i] = Ws[i];
        sWv[i] = Wv[i];
    }
    __syncthreads();
    const int j = threadIdx.x;
    const int part = j >> 6;       // 0: scalar, 1..3: vector components
    const int col = j & 63;
    const int pj = j - 64;
    const float* W = (part == 0) ? sWs : sWv;
    for (int n0 = blockIdx.x * 2; n0 < N; n0 += gridDim.x * 2) {
        const int n1 = n0 + 1;
        const bool has1 = n1 < N;
        sRow[0][j] = (part == 0) ? out[n0 * 64 + j] : out[N * 64 + n0 * 192 + pj];
        if (has1)
            sRow[1][j] = (part == 0) ? out[n1 * 64 + j] : out[N * 64 + n1 * 192 + pj];
        __syncthreads();
        float a0 = 0.f, a1 = 0.f;
        #pragma unroll
        for (int k4 = 0; k4 < 16; ++k4) {
            const float4 rA = *(const float4*)&sRow[0][part * 64 + 4 * k4];
            const float4 rB = *(const float4*)&sRow[1][part * 64 + 4 * k4];
            const float w0 = W[(4 * k4 + 0) * 64 + col];
            const float w1 = W[(4 * k4 + 1) * 64 + col];
            const float w2 = W[(4 * k4 + 2) * 64 + col];
            const float w3 = W[(4 * k4 + 3) * 64 + col];
            a0 += rA.x * w0 + rA.y * w1 + rA.z * w2 + rA.w * w3;
            a1 += rB.x * w0 + rB.y * w1 + rB.z * w2 + rB.w * w3;
        }
        __syncthreads();
        if (part == 0) out[n0 * 64 + j] = a0;
        else out[N * 64 + n0 * 192 + pj] = a0;
        if (has1) {
            if (part == 0) out[n1 * 64 + j] = a1;
            else out[N * 64 + n1 * 192 + pj] = a1;
        }
    }
}

// ---------------------------------------------------------------- full fallback
__global__ __launch_bounds__(512, 1) void edge_k(
    const int* __restrict__ src, const int* __restrict__ dst,
    const float* __restrict__ r_ij, const float* __restrict__ z0g,
    const float* __restrict__ z1g, const float* __restrict__ emb,
    const float* __restrict__ Wenc, const float* __restrict__ benc,
    const float* __restrict__ Wsrc, const float* __restrict__ bsrc,
    const float* __restrict__ Wdst, const float* __restrict__ bdst,
    const float* __restrict__ Wgate, const float* __restrict__ bgate,
    const float* __restrict__ Ws, const float* __restrict__ Wv,
    float* __restrict__ out, int N, int E)
{
    __shared__ float sWsrc[4096];
    __shared__ float sWdst[4096];
    __shared__ float sWg[16384];
    __shared__ float sWs[4096];
    __shared__ float sWv[4096];
    __shared__ float sWe[512];
    __shared__ float sB[64];
    __shared__ float sBg[256];
    __shared__ int sFl[2];

    if (threadIdx.x == 0) {
        const u32* ps = (const u32*)src;
        const u32* pd = (const u32*)dst;
        int s64 = 1, d64 = 1;
        for (int i = 1; i < 128; i += 2) {
            if (ps[i] != 0u) s64 = 0;
            if (pd[i] != 0u) d64 = 0;
        }
        sFl[0] = s64;
        sFl[1] = d64;
    }
    for (int i = threadIdx.x; i < 4096; i += 512) {
        sWsrc[i] = Wsrc[i];
        sWdst[i] = Wdst[i];
        sWs[i] = Ws[i];
        sWv[i] = Wv[i];
    }
    for (int i = threadIdx.x; i < 16384; i += 512) sWg[i] = Wgate[i];
    for (int i = threadIdx.x; i < 512; i += 512) sWe[i] = Wenc[i];
    if (threadIdx.x < 64)
        sB[threadIdx.x] = benc[threadIdx.x] + bsrc[threadIdx.x] + bdst[threadIdx.x];
    if (threadIdx.x < 256) sBg[threadIdx.x] = bgate[threadIdx.x];
    __syncthreads();

    const int wid = threadIdx.x >> 6, lane = threadIdx.x & 63;
    const int i64s = sFl[0], i64d = sFl[1];

    for (int e = blockIdx.x * 8 + wid; e < E; e += gridDim.x * 8) {
        const int s = i64s ? src[2 * e] : src[e];
        const int t = i64d ? dst[2 * e] : dst[e];
        if (s < 0 || s >= N || t < 0 || t >= N) continue;

        const float es = emb[s * 64 + lane];
        const float et = emb[t * 64 + lane];
        float de = sB[lane];
        #pragma unroll 8
        for (int k = 0; k < 64; ++k) {
            de += __shfl(es, k, 64) * sWsrc[(k << 6) + lane];
            de += __shfl(et, k, 64) * sWdst[(k << 6) + lane];
        }
        const float r0 = r_ij[e * 3 + 0];
        const float r1 = r_ij[e * 3 + 1];
        const float r2 = r_ij[e * 3 + 2];
        const float d = sqrtf(r0 * r0 + r1 * r1 + r2 * r2);
        #pragma unroll
        for (int m = 0; m < 8; ++m) {
            const float mu = (2.0f / 7.0f) * (float)m;
            const float tt = (d - mu) * 4.0f;
            de += __expf(-tt * tt) * sWe[m * 64 + lane];
        }

        const float v0 = r0 * 3.5f, v1 = r1 * 3.5f, v2 = r2 * 3.5f;
        const float inv = rsqrtf(1.0f + v0 * v0 + v1 * v1 + v2 * v2);
        const float h0 = v0 * inv, h1 = v1 * inv, h2 = v2 * inv;

        const float z0v = z0g[t * 64 + lane];
        const float za = z1g[t * 192 + lane];
        const float zb = z1g[t * 192 + 64 + lane];
        const float zc = z1g[t * 192 + 128 + lane];
        const float uu = h0 * za + h1 * zb + h2 * zc;

        float g0 = sBg[lane], g1 = sBg[64 + lane], g2 = sBg[128 + lane], g3 = sBg[192 + lane];
        #pragma unroll 8
        for (int k = 0; k < 64; ++k) {
            const float dk = __shfl(de, k, 64);
            const float* w = &sWg[(k << 8) + lane];
            g0 += dk * w[0];
            g1 += dk * w[64];
            g2 += dk * w[128];
            g3 += dk * w[192];
        }

        const float smsg = g0 * z0v + g1 * uu;
        const float vm0 = g2 * za + g3 * h0 * z0v;
        const float vm1 = g2 * zb + g3 * h1 * z0v;
        const float vm2 = g2 * zc + g3 * h2 * z0v;

        float p0 = 0.f, q0 = 0.f, q1 = 0.f, q2 = 0.f;
        #pragma unroll 8
        for (int k = 0; k < 64; ++k) {
            const float sk = __shfl(smsg, k, 64);
            const float a = __shfl(vm0, k, 64);
            const float b = __shfl(vm1, k, 64);
            const float c = __shfl(vm2, k, 64);
            p0 += sk * sWs[(k << 6) + lane];
            const float wv = sWv[(k << 6) + lane];
            q0 += a * wv;
            q1 += b * wv;
            q2 += c * wv;
        }

        atomicAdd(&out[s * 64 + lane], p0);
        const int b1 = N * 64 + s * 192 + lane;
        atomicAdd(&out[b1], q0);
        atomicAdd(&out[b1 + 64], q1);
        atomicAdd(&out[b1 + 128], q2);
    }
}

extern "C" void kernel_launch(void* const* d_in, const int* in_sizes, int n_in,
                              void* d_out, int out_size, void* d_ws, size_t ws_size,
                              hipStream_t stream) {
    const int* src = (const int*)d_in[0];
    const int* dst = (const int*)d_in[1];
    const float* r_ij = (const float*)d_in[2];
    const float* z0g  = (const float*)d_in[3];
    const float* z1g  = (const float*)d_in[4];
    const float* emb  = (const float*)d_in[5];
    const float* Wenc = (const float*)d_in[6];
    const float* benc = (const float*)d_in[7];
    const float* Wsrc = (const float*)d_in[8];
    const float* bsrc = (const float*)d_in[9];
    const float* Wdst = (const float*)d_in[10];
    const float* bdst = (const float*)d_in[11];
    const float* Wgate = (const float*)d_in[12];
    const float* bgate = (const float*)d_in[13];
    const float* Ws = (const float*)d_in[14];
    const float* Wv = (const float*)d_in[15];

    const int N = out_size / 256;                    // out0 N*64 + out1 N*192
    int E = in_sizes[0];
    if (in_sizes[2] / 3 < E) E = in_sizes[2] / 3;    // robustness

    zero_k<<<2048, 256, 0, stream>>>((float*)d_out, out_size);

    float* ws = (float*)d_ws;
    const size_t gsgd = 2u * (size_t)N * 256u;
    const size_t needGSGD = ((size_t)WS_GS + gsgd) * sizeof(float);

    if (ws != nullptr && ws_size >= needGSGD) {
        compose_k<<<73, 256, 0, stream>>>(Wsrc, Wdst, Wenc, benc, bsrc, bdst,
                                          Wgate, bgate, ws);
        float* GS = ws + WS_GS;
        float* GD = GS + (size_t)N * 256;
        nodepre2_k<<<512, 256, 0, stream>>>(emb, ws + WS_WSG, GS, N);
        nodepre2_k<<<512, 256, 0, stream>>>(emb, ws + WS_WDG, GD, N);
        edge_fast_k<<<2048, 256, 0, stream>>>(src, dst, r_ij, z0g, z1g, GS, GD,
                                              ws + WS_WEG, ws + WS_BALL,
                                              (float*)d_out, N, E);
        nodepost2_k<<<2048, 256, 0, stream>>>((float*)d_out, Ws, Wv, N);
    } else {
        edge_k<<<2048, 512, 0, stream>>>(src, dst, r_ij, z0g, z1g, emb, Wenc, benc,
                                         Wsrc, bsrc, Wdst, bdst, Wgate, bgate, Ws, Wv,
                                         (float*)d_out, N, E);
    }
}

// Round 5
// 677.640 us; speedup vs baseline: 2.3889x; 1.9054x over previous
//
#include <hip/hip_runtime.h>

typedef unsigned int u32;

// ---- workspace layout (float offsets) ----
// Combined gate weights Wc = [WsG | WdG] as [64][512] (k-major, 512 cols).
#define WS_WSG   0        // 64x512 combined  (32768 floats)
#define WS_WEG   32768    // 8x256 : Wenc @ Wgate   [m][j]
#define WS_BALL  34816    // 256   : (benc+bsrc+bdst) @ Wgate + bgate
#define WS_GS    35328    // N x 512 interleaved: G[n][0..255]=GS, [256..511]=GD

// ---------------------------------------------------------------- zero out
__global__ void zero_k(float* p, int n) {
    int i = blockIdx.x * blockDim.x + threadIdx.x;
    int st = gridDim.x * blockDim.x;
    for (; i < n; i += st) p[i] = 0.0f;
}

// ---------------------------------------------------------------- compose weights
// 73 blocks x 256 threads. r<64: combined [WsG|WdG] row; 64..71: WeG; 72: bias.
__global__ void compose_k(const float* __restrict__ Wsrc, const float* __restrict__ Wdst,
                          const float* __restrict__ Wenc, const float* __restrict__ benc,
                          const float* __restrict__ bsrc, const float* __restrict__ bdst,
                          const float* __restrict__ Wgate, const float* __restrict__ bgate,
                          float* __restrict__ ws) {
    const int j = threadIdx.x;           // 0..255
    const int r = blockIdx.x;            // 0..72
    if (r < 64) {
        float a = 0.f, b = 0.f;
        for (int c = 0; c < 64; ++c) {
            const float wg = Wgate[c * 256 + j];
            a += Wsrc[r * 64 + c] * wg;
            b += Wdst[r * 64 + c] * wg;
        }
        ws[WS_WSG + r * 512 + j] = a;
        ws[WS_WSG + r * 512 + 256 + j] = b;
    } else if (r < 72) {
        const int m = r - 64;
        float a = 0.f;
        for (int c = 0; c < 64; ++c) a += Wenc[m * 64 + c] * Wgate[c * 256 + j];
        ws[WS_WEG + m * 256 + j] = a;
    } else {
        float a = bgate[j];
        for (int c = 0; c < 64; ++c)
            a += (benc[c] + bsrc[c] + bdst[c]) * Wgate[c * 256 + j];
        ws[WS_BALL + j] = a;
    }
}

// ---------------------------------------------------------------- node precompute v3
// G[n][0..511] = emb[n][0..63] @ Wc[64][512].  512 threads, 16 nodes/tile.
// Thread: colquad c=tid&127 (cols 4c..4c+3), nodegroup g=tid>>7 (nodes g*4+i).
// Per k: 1x ds_read_b128 (W, distinct addrs) + 4x b32 uniform broadcast (emb)
// + 16 FMA. LDS 132 KB -> 1 block/CU.
__global__ __launch_bounds__(512, 1) void nodepre3_k(
    const float* __restrict__ emb, const float* __restrict__ Wc,
    float* __restrict__ G, int N) {
    __shared__ __align__(16) float sW[32768];    // 128 KB [k][512]
    __shared__ __align__(16) float sEm[1024];    // 16 node rows (contiguous)
    for (int i = threadIdx.x * 4; i < 32768; i += 2048)
        *(float4*)&sW[i] = *(const float4*)&Wc[i];

    const int c4 = (threadIdx.x & 127) << 2;     // col offset 0..508
    const int g = threadIdx.x >> 7;              // 0..3
    const int lim = N * 64;
    const int ntiles = (N + 15) >> 4;

    for (int tile = blockIdx.x; tile < ntiles; tile += gridDim.x) {
        const int n0 = tile << 4;
        const int base = n0 * 64;
        __syncthreads();   // prev-iter readers done (also covers initial sW load)
        for (int i = threadIdx.x * 4; i < 1024; i += 2048) {
            const int gi = base + i;
            *(float4*)&sEm[i] = (gi < lim) ? *(const float4*)&emb[gi]
                                           : make_float4(0.f, 0.f, 0.f, 0.f);
        }
        // 512*4 = 2048 floats per sweep covers 1024 in one pass for tid<256;
        // second half handled below (keep all threads busy):
        for (int i = 2048 + threadIdx.x * 4; i < 1024; i += 2048) { }
        __syncthreads();

        float4 a0 = {0,0,0,0}, a1 = {0,0,0,0}, a2 = {0,0,0,0}, a3 = {0,0,0,0};
        const float* e0p = &sEm[(g * 4 + 0) * 64];
        const float* e1p = &sEm[(g * 4 + 1) * 64];
        const float* e2p = &sEm[(g * 4 + 2) * 64];
        const float* e3p = &sEm[(g * 4 + 3) * 64];
        #pragma unroll 8
        for (int k = 0; k < 64; ++k) {
            const float4 w = *(const float4*)&sW[k * 512 + c4];
            const float e0 = e0p[k], e1 = e1p[k], e2 = e2p[k], e3 = e3p[k];
            a0.x += e0 * w.x; a0.y += e0 * w.y; a0.z += e0 * w.z; a0.w += e0 * w.w;
            a1.x += e1 * w.x; a1.y += e1 * w.y; a1.z += e1 * w.z; a1.w += e1 * w.w;
            a2.x += e2 * w.x; a2.y += e2 * w.y; a2.z += e2 * w.z; a2.w += e2 * w.w;
            a3.x += e3 * w.x; a3.y += e3 * w.y; a3.z += e3 * w.z; a3.w += e3 * w.w;
        }
        const int nb = n0 + g * 4;
        if (nb + 0 < N) *(float4*)&G[(size_t)(nb + 0) * 512 + c4] = a0;
        if (nb + 1 < N) *(float4*)&G[(size_t)(nb + 1) * 512 + c4] = a1;
        if (nb + 2 < N) *(float4*)&G[(size_t)(nb + 2) * 512 + c4] = a2;
        if (nb + 3 < N) *(float4*)&G[(size_t)(nb + 3) * 512 + c4] = a3;
    }
}

// ---------------------------------------------------------------- edge kernel (fast)
// EXACT round-1 structure (proven 440 us / 759 MB fetch / 500 MB write):
// one wave per edge, STRIDED traversal. Only change: G interleaved [n][512].
__global__ __launch_bounds__(256, 8) void edge_fast_k(
    const int* __restrict__ src, const int* __restrict__ dst,
    const float* __restrict__ r_ij, const float* __restrict__ z0g,
    const float* __restrict__ z1g, const float* __restrict__ G,
    const float* __restrict__ WeG, const float* __restrict__ ball,
    float* __restrict__ out, int N, int E) {
    __shared__ float sWe[2048];   // 8 KB
    __shared__ float sBall[256];  // 1 KB
    __shared__ int sFl[2];

    if (threadIdx.x == 0) {
        const u32* ps = (const u32*)src;
        const u32* pd = (const u32*)dst;
        int s64 = 1, d64 = 1;
        for (int i = 1; i < 128; i += 2) {
            if (ps[i] != 0u) s64 = 0;
            if (pd[i] != 0u) d64 = 0;
        }
        sFl[0] = s64;
        sFl[1] = d64;
    }
    for (int i = threadIdx.x; i < 2048; i += 256) sWe[i] = WeG[i];
    sBall[threadIdx.x] = ball[threadIdx.x];
    __syncthreads();

    const int wid = threadIdx.x >> 6, lane = threadIdx.x & 63;
    const int i64s = sFl[0], i64d = sFl[1];

    for (int e = blockIdx.x * 4 + wid; e < E; e += gridDim.x * 4) {
        const int s = i64s ? src[2 * e] : src[e];
        const int t = i64d ? dst[2 * e] : dst[e];
        if (s < 0 || s >= N || t < 0 || t >= N) continue;

        // issue all gathers up front
        const float* gs = G + (size_t)s * 512 + lane;
        const float* gd = G + (size_t)t * 512 + 256 + lane;
        const float a0 = gs[0], a1 = gs[64], a2 = gs[128], a3 = gs[192];
        const float b0 = gd[0], b1 = gd[64], b2 = gd[128], b3 = gd[192];
        const float z0v = z0g[t * 64 + lane];
        const float za = z1g[t * 192 + lane];
        const float zb = z1g[t * 192 + 64 + lane];
        const float zc = z1g[t * 192 + 128 + lane];
        const float r0 = r_ij[e * 3 + 0];
        const float r1 = r_ij[e * 3 + 1];
        const float r2 = r_ij[e * 3 + 2];

        float g0 = a0 + b0 + sBall[lane];
        float g1 = a1 + b1 + sBall[64 + lane];
        float g2 = a2 + b2 + sBall[128 + lane];
        float g3 = a3 + b3 + sBall[192 + lane];

        const float d = sqrtf(r0 * r0 + r1 * r1 + r2 * r2);
        #pragma unroll
        for (int m = 0; m < 8; ++m) {
            const float mu = 0.28571428571f * (float)m;   // linspace(0, 2, 8)
            const float tt = (d - mu) * 4.0f;             // / sigma, sigma = 0.25
            const float rm = __expf(-tt * tt);
            const float* wq = &sWe[(m << 8) + lane];
            g0 += rm * wq[0];
            g1 += rm * wq[64];
            g2 += rm * wq[128];
            g3 += rm * wq[192];
        }

        // r_hat = v/sqrt(1+|v|^2), v = r_ij*3.5
        const float v0 = r0 * 3.5f, v1 = r1 * 3.5f, v2 = r2 * 3.5f;
        const float inv = rsqrtf(1.0f + v0 * v0 + v1 * v1 + v2 * v2);
        const float h0 = v0 * inv, h1 = v1 * inv, h2 = v2 * inv;
        const float uu = h0 * za + h1 * zb + h2 * zc;     // r_hat . z1_j

        const float smsg = g0 * z0v + g1 * uu;
        const float vm0 = g2 * za + g3 * h0 * z0v;
        const float vm1 = g2 * zb + g3 * h1 * z0v;
        const float vm2 = g2 * zc + g3 * h2 * z0v;

        atomicAdd(&out[s * 64 + lane], smsg);
        const int bo = N * 64 + s * 192 + lane;
        atomicAdd(&out[bo], vm0);
        atomicAdd(&out[bo + 64], vm1);
        atomicAdd(&out[bo + 128], vm2);
    }
}

// ---------------------------------------------------------------- node epilogue v3
// out is a contiguous (4N)x64 row-major matrix: rows 0..N-1 are S (use Ws),
// rows N..4N-1 are V components (use Wv). In-place row-wise matmul.
// 64 rows/tile staged in LDS with +1 pad; thread: 4 cols x 4 rows.
__global__ __launch_bounds__(256, 3) void nodepost3_k(
    float* __restrict__ out, const float* __restrict__ Ws,
    const float* __restrict__ Wv, int N) {
    __shared__ __align__(16) float sW[8192];     // [0..4095]=Ws, [4096..]=Wv
    __shared__ float sR[64 * 65];                // 64 rows, pad 65
    for (int i = threadIdx.x * 4; i < 8192; i += 1024) {
        *(float4*)&sW[i] = (i < 4096) ? *(const float4*)&Ws[i]
                                      : *(const float4*)&Wv[i - 4096];
    }
    const int c4 = (threadIdx.x & 15) << 2;      // col offset 0..60
    const int rq = threadIdx.x >> 4;             // 0..15 -> rows rq*4..+3
    const int totalRows = 4 * N;
    const int lim = totalRows * 64;
    const int ntiles = (totalRows + 63) >> 6;

    for (int tile = blockIdx.x; tile < ntiles; tile += gridDim.x) {
        const int r0 = tile << 6;
        __syncthreads();   // prev-iter readers done (also covers sW load)
        for (int i = threadIdx.x; i < 4096; i += 256) {
            const int gi = r0 * 64 + i;
            sR[(i >> 6) * 65 + (i & 63)] = (gi < lim) ? out[gi] : 0.f;
        }
        __syncthreads();

        const int rb = rq << 2;                  // local row base
        const int gr = r0 + rb;                  // global row base
        const int o0 = (gr + 0 < N) ? 0 : 4096;
        const int o3 = (gr + 3 < N) ? 0 : 4096;
        float4 a0 = {0,0,0,0}, a1 = {0,0,0,0}, a2 = {0,0,0,0}, a3 = {0,0,0,0};
        const float* rp0 = &sR[(rb + 0) * 65];
        const float* rp1 = &sR[(rb + 1) * 65];
        const float* rp2 = &sR[(rb + 2) * 65];
        const float* rp3 = &sR[(rb + 3) * 65];
        if (o0 == o3) {                          // uniform W for all 4 rows
            const float* wb = &sW[o0 + c4];
            #pragma unroll 8
            for (int k = 0; k < 64; ++k) {
                const float4 w = *(const float4*)&wb[k * 64];
                const float e0 = rp0[k], e1 = rp1[k], e2 = rp2[k], e3 = rp3[k];
                a0.x += e0 * w.x; a0.y += e0 * w.y; a0.z += e0 * w.z; a0.w += e0 * w.w;
                a1.x += e1 * w.x; a1.y += e1 * w.y; a1.z += e1 * w.z; a1.w += e1 * w.w;
                a2.x += e2 * w.x; a2.y += e2 * w.y; a2.z += e2 * w.z; a2.w += e2 * w.w;
                a3.x += e3 * w.x; a3.y += e3 * w.y; a3.z += e3 * w.z; a3.w += e3 * w.w;
            }
        } else {                                 // boundary tile (rare)
            const int o1 = (gr + 1 < N) ? 0 : 4096;
            const int o2 = (gr + 2 < N) ? 0 : 4096;
            #pragma unroll 4
            for (int k = 0; k < 64; ++k) {
                const float4 w0 = *(const float4*)&sW[o0 + k * 64 + c4];
                const float4 w1 = *(const float4*)&sW[o1 + k * 64 + c4];
                const float4 w2 = *(const float4*)&sW[o2 + k * 64 + c4];
                const float4 w3 = *(const float4*)&sW[o3 + k * 64 + c4];
                const float e0 = rp0[k], e1 = rp1[k], e2 = rp2[k], e3 = rp3[k];
                a0.x += e0 * w0.x; a0.y += e0 * w0.y; a0.z += e0 * w0.z; a0.w += e0 * w0.w;
                a1.x += e1 * w1.x; a1.y += e1 * w1.y; a1.z += e1 * w1.z; a1.w += e1 * w1.w;
                a2.x += e2 * w2.x; a2.y += e2 * w2.y; a2.z += e2 * w2.z; a2.w += e2 * w2.w;
                a3.x += e3 * w3.x; a3.y += e3 * w3.y; a3.z += e3 * w3.z; a3.w += e3 * w3.w;
            }
        }
        if (gr + 0 < totalRows) *(float4*)&out[(size_t)(gr + 0) * 64 + c4] = a0;
        if (gr + 1 < totalRows) *(float4*)&out[(size_t)(gr + 1) * 64 + c4] = a1;
        if (gr + 2 < totalRows) *(float4*)&out[(size_t)(gr + 2) * 64 + c4] = a2;
        if (gr + 3 < totalRows) *(float4*)&out[(size_t)(gr + 3) * 64 + c4] = a3;
    }
}

// ---------------------------------------------------------------- full fallback
__global__ __launch_bounds__(512, 1) void edge_k(
    const int* __restrict__ src, const int* __restrict__ dst,
    const float* __restrict__ r_ij, const float* __restrict__ z0g,
    const float* __restrict__ z1g, const float* __restrict__ emb,
    const float* __restrict__ Wenc, const float* __restrict__ benc,
    const float* __restrict__ Wsrc, const float* __restrict__ bsrc,
    const float* __restrict__ Wdst, const float* __restrict__ bdst,
    const float* __restrict__ Wgate, const float* __restrict__ bgate,
    const float* __restrict__ Ws, const float* __restrict__ Wv,
    float* __restrict__ out, int N, int E)
{
    __shared__ float sWsrc[4096];
    __shared__ float sWdst[4096];
    __shared__ float sWg[16384];
    __shared__ float sWs[4096];
    __shared__ float sWv[4096];
    __shared__ float sWe[512];
    __shared__ float sB[64];
    __shared__ float sBg[256];
    __shared__ int sFl[2];

    if (threadIdx.x == 0) {
        const u32* ps = (const u32*)src;
        const u32* pd = (const u32*)dst;
        int s64 = 1, d64 = 1;
        for (int i = 1; i < 128; i += 2) {
            if (ps[i] != 0u) s64 = 0;
            if (pd[i] != 0u) d64 = 0;
        }
        sFl[0] = s64;
        sFl[1] = d64;
    }
    for (int i = threadIdx.x; i < 4096; i += 512) {
        sWsrc[i] = Wsrc[i];
        sWdst[i] = Wdst[i];
        sWs[i] = Ws[i];
        sWv[i] = Wv[i];
    }
    for (int i = threadIdx.x; i < 16384; i += 512) sWg[i] = Wgate[i];
    for (int i = threadIdx.x; i < 512; i += 512) sWe[i] = Wenc[i];
    if (threadIdx.x < 64)
        sB[threadIdx.x] = benc[threadIdx.x] + bsrc[threadIdx.x] + bdst[threadIdx.x];
    if (threadIdx.x < 256) sBg[threadIdx.x] = bgate[threadIdx.x];
    __syncthreads();

    const int wid = threadIdx.x >> 6, lane = threadIdx.x & 63;
    const int i64s = sFl[0], i64d = sFl[1];

    for (int e = blockIdx.x * 8 + wid; e < E; e += gridDim.x * 8) {
        const int s = i64s ? src[2 * e] : src[e];
        const int t = i64d ? dst[2 * e] : dst[e];
        if (s < 0 || s >= N || t < 0 || t >= N) continue;

        const float es = emb[s * 64 + lane];
        const float et = emb[t * 64 + lane];
        float de = sB[lane];
        #pragma unroll 8
        for (int k = 0; k < 64; ++k) {
            de += __shfl(es, k, 64) * sWsrc[(k << 6) + lane];
            de += __shfl(et, k, 64) * sWdst[(k << 6) + lane];
        }
        const float r0 = r_ij[e * 3 + 0];
        const float r1 = r_ij[e * 3 + 1];
        const float r2 = r_ij[e * 3 + 2];
        const float d = sqrtf(r0 * r0 + r1 * r1 + r2 * r2);
        #pragma unroll
        for (int m = 0; m < 8; ++m) {
            const float mu = (2.0f / 7.0f) * (float)m;
            const float tt = (d - mu) * 4.0f;
            de += __expf(-tt * tt) * sWe[m * 64 + lane];
        }

        const float v0 = r0 * 3.5f, v1 = r1 * 3.5f, v2 = r2 * 3.5f;
        const float inv = rsqrtf(1.0f + v0 * v0 + v1 * v1 + v2 * v2);
        const float h0 = v0 * inv, h1 = v1 * inv, h2 = v2 * inv;

        const float z0v = z0g[t * 64 + lane];
        const float za = z1g[t * 192 + lane];
        const float zb = z1g[t * 192 + 64 + lane];
        const float zc = z1g[t * 192 + 128 + lane];
        const float uu = h0 * za + h1 * zb + h2 * zc;

        float g0 = sBg[lane], g1 = sBg[64 + lane], g2 = sBg[128 + lane], g3 = sBg[192 + lane];
        #pragma unroll 8
        for (int k = 0; k < 64; ++k) {
            const float dk = __shfl(de, k, 64);
            const float* w = &sWg[(k << 8) + lane];
            g0 += dk * w[0];
            g1 += dk * w[64];
            g2 += dk * w[128];
            g3 += dk * w[192];
        }

        const float smsg = g0 * z0v + g1 * uu;
        const float vm0 = g2 * za + g3 * h0 * z0v;
        const float vm1 = g2 * zb + g3 * h1 * z0v;
        const float vm2 = g2 * zc + g3 * h2 * z0v;

        float p0 = 0.f, q0 = 0.f, q1 = 0.f, q2 = 0.f;
        #pragma unroll 8
        for (int k = 0; k < 64; ++k) {
            const float sk = __shfl(smsg, k, 64);
            const float a = __shfl(vm0, k, 64);
            const float b = __shfl(vm1, k, 64);
            const float c = __shfl(vm2, k, 64);
            p0 += sk * sWs[(k << 6) + lane];
            const float wv = sWv[(k << 6) + lane];
            q0 += a * wv;
            q1 += b * wv;
            q2 += c * wv;
        }

        atomicAdd(&out[s * 64 + lane], p0);
        const int b1 = N * 64 + s * 192 + lane;
        atomicAdd(&out[b1], q0);
        atomicAdd(&out[b1 + 64], q1);
        atomicAdd(&out[b1 + 128], q2);
    }
}

extern "C" void kernel_launch(void* const* d_in, const int* in_sizes, int n_in,
                              void* d_out, int out_size, void* d_ws, size_t ws_size,
                              hipStream_t stream) {
    const int* src = (const int*)d_in[0];
    const int* dst = (const int*)d_in[1];
    const float* r_ij = (const float*)d_in[2];
    const float* z0g  = (const float*)d_in[3];
    const float* z1g  = (const float*)d_in[4];
    const float* emb  = (const float*)d_in[5];
    const float* Wenc = (const float*)d_in[6];
    const float* benc = (const float*)d_in[7];
    const float* Wsrc = (const float*)d_in[8];
    const float* bsrc = (const float*)d_in[9];
    const float* Wdst = (const float*)d_in[10];
    const float* bdst = (const float*)d_in[11];
    const float* Wgate = (const float*)d_in[12];
    const float* bgate = (const float*)d_in[13];
    const float* Ws = (const float*)d_in[14];
    const float* Wv = (const float*)d_in[15];

    const int N = out_size / 256;                    // out0 N*64 + out1 N*192
    int E = in_sizes[0];
    if (in_sizes[2] / 3 < E) E = in_sizes[2] / 3;    // robustness

    zero_k<<<2048, 256, 0, stream>>>((float*)d_out, out_size);

    float* ws = (float*)d_ws;
    const size_t need = ((size_t)WS_GS + (size_t)N * 512u) * sizeof(float);

    if (ws != nullptr && ws_size >= need) {
        compose_k<<<73, 256, 0, stream>>>(Wsrc, Wdst, Wenc, benc, bsrc, bdst,
                                          Wgate, bgate, ws);
        float* G = ws + WS_GS;
        nodepre3_k<<<256, 512, 0, stream>>>(emb, ws + WS_WSG, G, N);
        edge_fast_k<<<2048, 256, 0, stream>>>(src, dst, r_ij, z0g, z1g, G,
                                              ws + WS_WEG, ws + WS_BALL,
                                              (float*)d_out, N, E);
        nodepost3_k<<<2048, 256, 0, stream>>>((float*)d_out, Ws, Wv, N);
    } else {
        edge_k<<<2048, 512, 0, stream>>>(src, dst, r_ij, z0g, z1g, emb, Wenc, benc,
                                         Wsrc, bsrc, Wdst, bdst, Wgate, bgate, Ws, Wv,
                                         (float*)d_out, N, E);
    }
}